// Round 8
// baseline (49.205 us; speedup 1.0000x reference)
//
#include <hip/hip_runtime.h>

// h_t = tanh(x_t + 0.97*h_{t-1}), B=128, C=1, T=262144, fp32.
//
// R8: persistent software-pipelined streaming. Same dense-tile geometry as
// R7 (region = 64 chunks x 32 main floats + 64-float warm head; every input
// byte fetched once; contiguous read AND write streams; warm W=64 keeps
// absmax at the 3.9e-3 exp2/rcp floor). Change: 2048 persistent waves
// (1024 blocks x 2, exactly resident, 8 waves/CU), each wave runs 8
// consecutive regions and issues region r+1's global loads BEFORE computing
// region r -> loads/stores stay in flight across the ~3000-cycle serial
// tanh chain instead of bursting once per short-lived block. R6->R7 A/B
// showed occupancy alone is null; this tests burst-structure vs ceiling.
// LDS quad-swizzle p = q ^ ((q>>3)&7): all phases uniform 8 lanes per
// 16B-column = max-rate b128. Per-wave-private tiles -> zero barriers.

#define BB 128
#define TT 262144
#define REG 2048                  // main floats per region (64 lanes x 32)
#define WPR 16                    // waves per row
#define RPW ((TT / REG) / WPR)    // 8 regions per wave
#define NBLK ((BB * WPR) / 2)     // 1024 blocks, 2 waves each

typedef float f32x4 __attribute__((ext_vector_type(4)));

__device__ __forceinline__ int swq(int q) { return q ^ ((q >> 3) & 7); }

__global__ __launch_bounds__(128) void ipe_kernel(const float* __restrict__ x,
                                                  float* __restrict__ y) {
    const int lane = threadIdx.x & 63;
    const int wv   = threadIdx.x >> 6;
    const int w    = blockIdx.x * 2 + wv;       // 0..2047
    const int row  = w >> 4;                    // 128 rows
    const int p    = w & 15;
    const size_t rowBase = (size_t)row * TT;
    const long   base = (long)p * (RPW * REG);  // first region start (float idx)

    __shared__ float tile_all[2][528 * 4];      // 8448 B per wave
    float* tile = tile_all[wv];

    const float C2 = 2.885390081777926815f;     // 2*log2(e)
    const float K2 = 0.97f * C2;

    f32x4 pfA[8], phA, pfB[8], phB;

    auto load = [&](f32x4 (&pf)[8], f32x4& ph, long t0) {
        #pragma unroll
        for (int m = 0; m < 8; ++m)
            pf[m] = *reinterpret_cast<const f32x4*>(x + rowBase + t0 + 256 * m + 4 * lane);
        if (lane < 16) {
            const long T = t0 - 64 + 4 * lane;
            if (T >= 0) ph = *reinterpret_cast<const f32x4*>(x + rowBase + T);
            else        ph = (f32x4){0.f, 0.f, 0.f, 0.f};   // x=0 keeps h=0 (row start)
        }
    };

    auto process = [&](f32x4 (&pf)[8], f32x4& ph, long t0) {
        // ---- stage region (quads: head 0..15, main 16..527) ----
        #pragma unroll
        for (int m = 0; m < 8; ++m)
            *reinterpret_cast<f32x4*>(&tile[4 * swq(16 + 64 * m + lane)]) = pf[m];
        if (lane < 16)
            *reinterpret_cast<f32x4*>(&tile[4 * swq(lane)]) = ph;
        asm volatile("" ::: "memory");

        // ---- warm reads: lane's quads 8l..8l+15 ----
        float xv[32];
        f32x4 pw[8];
        #pragma unroll
        for (int t = 0; t < 8; ++t) {
            f32x4 v = *reinterpret_cast<const f32x4*>(&tile[4 * swq(8 * lane + t)]);
            xv[4 * t + 0] = v.x; xv[4 * t + 1] = v.y;
            xv[4 * t + 2] = v.z; xv[4 * t + 3] = v.w;
        }
        #pragma unroll
        for (int t = 0; t < 8; ++t)
            pw[t] = *reinterpret_cast<const f32x4*>(&tile[4 * swq(8 * lane + 8 + t)]);

        float h = 0.f;
        #pragma unroll
        for (int k = 0; k < 32; ++k) {          // warm steps 0..31
            float z2 = fmaf(K2, h, xv[k] * C2);
            float ez = __builtin_amdgcn_exp2f(z2);
            float rc = __builtin_amdgcn_rcpf(ez + 1.0f);
            h = fmaf(-2.0f, rc, 1.0f);
        }

        // main-chunk read (latency hides under warm half 2)
        #pragma unroll
        for (int t = 0; t < 8; ++t) {
            f32x4 v = *reinterpret_cast<const f32x4*>(&tile[4 * swq(16 + 8 * lane + t)]);
            xv[4 * t + 0] = v.x; xv[4 * t + 1] = v.y;
            xv[4 * t + 2] = v.z; xv[4 * t + 3] = v.w;
        }

        #pragma unroll
        for (int t = 0; t < 8; ++t) {           // warm steps 32..63
            float z2, ez, rc;
            z2 = fmaf(K2, h, pw[t].x * C2); ez = __builtin_amdgcn_exp2f(z2);
            rc = __builtin_amdgcn_rcpf(ez + 1.0f); h = fmaf(-2.0f, rc, 1.0f);
            z2 = fmaf(K2, h, pw[t].y * C2); ez = __builtin_amdgcn_exp2f(z2);
            rc = __builtin_amdgcn_rcpf(ez + 1.0f); h = fmaf(-2.0f, rc, 1.0f);
            z2 = fmaf(K2, h, pw[t].z * C2); ez = __builtin_amdgcn_exp2f(z2);
            rc = __builtin_amdgcn_rcpf(ez + 1.0f); h = fmaf(-2.0f, rc, 1.0f);
            z2 = fmaf(K2, h, pw[t].w * C2); ez = __builtin_amdgcn_exp2f(z2);
            rc = __builtin_amdgcn_rcpf(ez + 1.0f); h = fmaf(-2.0f, rc, 1.0f);
        }

        // ---- main chain: 32 steps, keep outputs ----
        #pragma unroll
        for (int k = 0; k < 32; ++k) {
            float z2 = fmaf(K2, h, xv[k] * C2);
            float ez = __builtin_amdgcn_exp2f(z2);
            float rc = __builtin_amdgcn_rcpf(ez + 1.0f);
            h = fmaf(-2.0f, rc, 1.0f);
            xv[k] = h;
        }

        // ---- writeback, then contiguous streaming stores ----
        asm volatile("" ::: "memory");
        #pragma unroll
        for (int t = 0; t < 8; ++t) {
            f32x4 v;
            v.x = xv[4 * t + 0]; v.y = xv[4 * t + 1];
            v.z = xv[4 * t + 2]; v.w = xv[4 * t + 3];
            *reinterpret_cast<f32x4*>(&tile[4 * swq(16 + 8 * lane + t)]) = v;
        }
        asm volatile("" ::: "memory");
        #pragma unroll
        for (int m = 0; m < 8; ++m) {
            f32x4 v = *reinterpret_cast<const f32x4*>(&tile[4 * swq(16 + 64 * m + lane)]);
            *reinterpret_cast<f32x4*>(y + rowBase + t0 + 256 * m + 4 * lane) = v;
        }
        asm volatile("" ::: "memory");
    };

    // ---- persistent 2-deep pipeline over RPW consecutive regions ----
    load(pfA, phA, base);
    #pragma unroll 1
    for (int rr = 0; rr < RPW; rr += 2) {
        load(pfB, phB, base + (long)(rr + 1) * REG);      // prefetch next
        process(pfA, phA, base + (long)rr * REG);
        if (rr + 2 < RPW) load(pfA, phA, base + (long)(rr + 2) * REG);
        process(pfB, phB, base + (long)(rr + 1) * REG);
    }
}

extern "C" void kernel_launch(void* const* d_in, const int* in_sizes, int n_in,
                              void* d_out, int out_size, void* d_ws, size_t ws_size,
                              hipStream_t stream) {
    const float* x = (const float*)d_in[0];
    float* y = (float*)d_out;
    ipe_kernel<<<dim3(NBLK), dim3(128), 0, stream>>>(x, y);
}

// Round 9
// 46.151 us; speedup vs baseline: 1.0662x; 1.0662x over previous
//
#include <hip/hip_runtime.h>

// h_t = tanh(x_t + 0.97*h_{t-1}), B=128, C=1, T=262144, fp32.
//
// FINAL (= R7, best measured 46.28 us, 92% of the 6.29 TB/s copy ceiling on
// logical 268 MB read+write traffic).
//
// Dense streaming chunked-scan: each wave owns a contiguous region
// [t0-64, t0+2048): 64 chunks of L=32 outputs (one per lane) + 64-float warm
// prefix. Lane l warms on floats [32l, 32l+64) of the region (the two
// previous chunks) then runs its 32 main steps. Warm W=64: contraction
// 0.97*(1-h^2)/step makes boundary error negligible (absmax 3.9e-3 =
// exp2/rcp rounding floor, W-independent). Every input byte fetched once
// (warm region == neighbor chunks' main data, shared via LDS); reads AND
// writes are pure contiguous streams. Tile 8.4 KB/wave, 2 waves/block ->
// 18 waves/CU. LDS quad-swizzle q^((q>>3)&7): uniform 8 lanes/quad-bank in
// all phases. Per-wave-private tiles -> zero barriers (in-order LDS per
// wave + compiler fences). XCD-swizzled block ids for L2 locality.
//
// Falsified alternatives (A/B'd): strided partial-tile reads (~4 TB/s DRAM
// efficiency cap), occupancy 2x (null), persistent pipelined waves (-6%),
// nontemporal stores (no FETCH change), LDS-in-critical-path (null).

#define BB 128
#define TT 262144
#define CHL 32                    // main steps per lane
#define WW 64                     // warm steps
#define WPR 128                   // waves per row = (TT/CHL)/64
#define NBLK ((BB * WPR) / 2)     // 8192 blocks, 2 waves each

typedef float f32x4 __attribute__((ext_vector_type(4)));

__device__ __forceinline__ int swq(int q) { return q ^ ((q >> 3) & 7); }

__global__ __launch_bounds__(128) void ipe_kernel(const float* __restrict__ x,
                                                  float* __restrict__ y) {
    const int lane = threadIdx.x & 63;
    const int wv   = threadIdx.x >> 6;
    // XCD-aware bijective swizzle (NBLK % 8 == 0)
    const int bid  = (blockIdx.x & 7) * (NBLK >> 3) + (blockIdx.x >> 3);
    const int w    = bid * 2 + wv;
    const int row  = w >> 7;                  // / WPR
    const int g    = w & (WPR - 1);
    const size_t rowBase = (size_t)row * TT;
    const long   t0 = (long)g * (64 * CHL);   // wave's first output float

    __shared__ float tile_all[2][528 * 4];    // 8448 B per wave
    float* tile = tile_all[wv];

    // ---- load region: main [t0, t0+2048) + head [t0-64, t0) ----
    f32x4 pf[8], ph;
    #pragma unroll
    for (int m = 0; m < 8; ++m)
        pf[m] = *reinterpret_cast<const f32x4*>(x + rowBase + t0 + 256 * m + 4 * lane);
    if (lane < 16) {
        const long T = t0 - WW + 4 * lane;
        if (T >= 0) ph = *reinterpret_cast<const f32x4*>(x + rowBase + T);
        else        ph = (f32x4){0.f, 0.f, 0.f, 0.f};   // x=0 keeps h=0 (row start)
    }

    // ---- stage -> LDS (quad q = region_float/4, swizzled) ----
    #pragma unroll
    for (int m = 0; m < 8; ++m)
        *reinterpret_cast<f32x4*>(&tile[4 * swq(16 + 64 * m + lane)]) = pf[m];
    if (lane < 16)
        *reinterpret_cast<f32x4*>(&tile[4 * swq(lane)]) = ph;
    asm volatile("" ::: "memory");

    // ---- reads: warm half 1 -> xv, warm half 2 -> pf (reuse) ----
    float xv[32];
    #pragma unroll
    for (int t = 0; t < 8; ++t) {
        f32x4 v = *reinterpret_cast<const f32x4*>(&tile[4 * swq(8 * lane + t)]);
        xv[4 * t + 0] = v.x; xv[4 * t + 1] = v.y;
        xv[4 * t + 2] = v.z; xv[4 * t + 3] = v.w;
    }
    #pragma unroll
    for (int t = 0; t < 8; ++t)
        pf[t] = *reinterpret_cast<const f32x4*>(&tile[4 * swq(8 * lane + 8 + t)]);

    // tanh(z) = 1 - 2/(exp2(2z*log2e)+1)
    const float C2 = 2.885390081777926815f;   // 2*log2(e)
    const float K2 = 0.97f * C2;
    float h = 0.f;

    #pragma unroll
    for (int k = 0; k < 32; ++k) {            // warm steps 0..31
        float z2 = fmaf(K2, h, xv[k] * C2);
        float ez = __builtin_amdgcn_exp2f(z2);
        float rc = __builtin_amdgcn_rcpf(ez + 1.0f);
        h = fmaf(-2.0f, rc, 1.0f);
    }

    // main-chunk read -> xv (issued here; latency hides under warm half 2)
    #pragma unroll
    for (int t = 0; t < 8; ++t) {
        f32x4 v = *reinterpret_cast<const f32x4*>(&tile[4 * swq(16 + 8 * lane + t)]);
        xv[4 * t + 0] = v.x; xv[4 * t + 1] = v.y;
        xv[4 * t + 2] = v.z; xv[4 * t + 3] = v.w;
    }

    #pragma unroll
    for (int t = 0; t < 8; ++t) {             // warm steps 32..63 (from pf)
        float z2, ez, rc;
        z2 = fmaf(K2, h, pf[t].x * C2); ez = __builtin_amdgcn_exp2f(z2);
        rc = __builtin_amdgcn_rcpf(ez + 1.0f); h = fmaf(-2.0f, rc, 1.0f);
        z2 = fmaf(K2, h, pf[t].y * C2); ez = __builtin_amdgcn_exp2f(z2);
        rc = __builtin_amdgcn_rcpf(ez + 1.0f); h = fmaf(-2.0f, rc, 1.0f);
        z2 = fmaf(K2, h, pf[t].z * C2); ez = __builtin_amdgcn_exp2f(z2);
        rc = __builtin_amdgcn_rcpf(ez + 1.0f); h = fmaf(-2.0f, rc, 1.0f);
        z2 = fmaf(K2, h, pf[t].w * C2); ez = __builtin_amdgcn_exp2f(z2);
        rc = __builtin_amdgcn_rcpf(ez + 1.0f); h = fmaf(-2.0f, rc, 1.0f);
    }

    // ---- main chain: 32 steps, keep outputs ----
    #pragma unroll
    for (int k = 0; k < 32; ++k) {
        float z2 = fmaf(K2, h, xv[k] * C2);
        float ez = __builtin_amdgcn_exp2f(z2);
        float rc = __builtin_amdgcn_rcpf(ez + 1.0f);
        h = fmaf(-2.0f, rc, 1.0f);
        xv[k] = h;
    }

    // ---- writeback h's, then contiguous streaming stores ----
    asm volatile("" ::: "memory");
    #pragma unroll
    for (int t = 0; t < 8; ++t) {
        f32x4 v;
        v.x = xv[4 * t + 0]; v.y = xv[4 * t + 1];
        v.z = xv[4 * t + 2]; v.w = xv[4 * t + 3];
        *reinterpret_cast<f32x4*>(&tile[4 * swq(16 + 8 * lane + t)]) = v;
    }
    asm volatile("" ::: "memory");

    #pragma unroll
    for (int m = 0; m < 8; ++m) {
        f32x4 v = *reinterpret_cast<const f32x4*>(&tile[4 * swq(16 + 64 * m + lane)]);
        *reinterpret_cast<f32x4*>(y + rowBase + t0 + 256 * m + 4 * lane) = v;
    }
}

extern "C" void kernel_launch(void* const* d_in, const int* in_sizes, int n_in,
                              void* d_out, int out_size, void* d_ws, size_t ws_size,
                              hipStream_t stream) {
    const float* x = (const float*)d_in[0];
    float* y = (float*)d_out;
    ipe_kernel<<<dim3(NBLK), dim3(128), 0, stream>>>(x, y);
}